// Round 14
// baseline (26.587 us; speedup 1.0000x reference)
//
#include <hip/hip_runtime.h>
#include <hip/hip_bf16.h>

// TT embedding: vocab 65536, dim 1024, rank 16.
// out[v,d] = sum_{r1..r4} c0[0,i0,r1] c1[r1,i1,r2] c2[r2,i2,r3] c3[r3,i3,r4] c4[r4,i4,0]
//   i0=v>>11, i1=(v>>6)&31, i2=(v>>1)&31, i3=(v&1)*16+(d>>6), i4=d&63
//
// R13 lesson: fp16-c4 trick self-defeated (cvt hoist re-ballooned VGPR);
// occupancy never actually rose past 4 waves/SIMD. R14: VGPR <= 64 BY
// CONSTRUCTION, enforced with __launch_bounds__(256, 8):
//   - c4 slice = 1 column/lane = 16 fp32 regs (was 64)
//   - stage 4: all 64 lanes process one token at a time (2 per wave);
//     w4-row reads are wave-UNIFORM ds_read_b128 broadcasts (conflict-free);
//     stores are 256B/instr contiguous dword streams (fill-kernel pattern)
//   - stages 1-3 unchanged from R11/R13 (fp32, same FMA orders -> absmax 0)
//   - zero barriers (all LDS RAW is same-wave); 2048 blocks x 4 waves
//     = 8 waves/SIMD resident (LDS 10.5KB x 8 blocks/CU = 84KB < 160KB)

#define RSTRIDE 20          // words per w4 row
#define GSTRIDE 328         // 16*20+8; mod 32 = 8 -> slabs bank-staggered

__global__ __launch_bounds__(256, 8) void tt_embed_kernel(
    const float* __restrict__ c0,   // 32*16
    const float* __restrict__ c1,   // 16*32*16
    const float* __restrict__ c2,   // 16*32*16
    const float* __restrict__ c3,   // 16*32*16
    const float* __restrict__ c4,   // 16*64
    const int*   __restrict__ idx,  // n_tokens
    float*       __restrict__ out,  // n_tokens x 1024
    int n_tokens)
{
    const int t   = threadIdx.x;
    const int tl  = t >> 5;          // token slot in block (0..7)
    const int l32 = t & 31;          // lane within token (stages 1-3)
    const int r   = t & 15;          // rank lane
    const int l   = t & 63;          // lane in wave = output column (stage 4)
    const int wid = t >> 6;          // wave in block (0..3)
    const int token = blockIdx.x * 8 + tl;
    const int v = (token < n_tokens) ? idx[token] : 0;

    __shared__ float w4s[8 * GSTRIDE];   // 10.5 KB

    // ---- c4: ONE column per lane -> 16 VGPRs. Coalesced 256B loads.
    float c4v[16];
    #pragma unroll
    for (int r4 = 0; r4 < 16; ++r4)
        c4v[r4] = c4[(r4 << 6) + l];

    // ---- Stage 1: w2[r] = sum_r1 c0[i0,r1] * c1[r1,i1,r]  (2x redundant)
    float w2r = 0.f;
    {
        const int i0 = (v >> 11) & 31;
        const int i1 = (v >> 6) & 31;
        #pragma unroll
        for (int r1 = 0; r1 < 16; ++r1)
            w2r = fmaf(c0[i0 * 16 + r1], c1[(r1 * 32 + i1) * 16 + r], w2r);
    }

    // ---- Stage 2: w3[r] = sum_r2 w2[r2] * c2[r2,i2,r]
    float w3r = 0.f;
    {
        const int i2 = (v >> 1) & 31;
        #pragma unroll
        for (int r2 = 0; r2 < 16; ++r2)
            w3r = fmaf(__shfl(w2r, r2, 16), c2[(r2 * 32 + i2) * 16 + r], w3r);
    }

    // ---- Stage 3: token's 32 lanes read its 1KB c3 block as two contiguous
    // 512B halves per r3. Lane l32 owns quarter (l32&3) of rows (l32>>2) and
    // 8+(l32>>2). Same per-element r3 order as R11 (absmax 0.0).
    {
        const int vlow16 = (v & 1) << 4;
        float4 a0 = {0,0,0,0}, a1 = {0,0,0,0};
        #pragma unroll
        for (int r3 = 0; r3 < 16; ++r3) {
            const float wv = __shfl(w3r, r3, 16);
            const float* base = c3 + ((r3 * 32 + vlow16) << 4);
            const float4 b0 = *(const float4*)(base + (l32 << 2));        // rows 0..7
            const float4 b1 = *(const float4*)(base + 128 + (l32 << 2));  // rows 8..15
            a0.x = fmaf(wv, b0.x, a0.x); a0.y = fmaf(wv, b0.y, a0.y);
            a0.z = fmaf(wv, b0.z, a0.z); a0.w = fmaf(wv, b0.w, a0.w);
            a1.x = fmaf(wv, b1.x, a1.x); a1.y = fmaf(wv, b1.y, a1.y);
            a1.z = fmaf(wv, b1.z, a1.z); a1.w = fmaf(wv, b1.w, a1.w);
        }
        // same-wave LDS scatter (no barrier)
        float* sb = &w4s[tl * GSTRIDE + ((l32 & 3) << 2)];
        *(float4*)(sb + ((l32 >> 2)    ) * RSTRIDE) = a0;
        *(float4*)(sb + (8 + (l32 >> 2)) * RSTRIDE) = a1;
    }

    // ---- Stage 4: wave processes its 2 tokens sequentially; all 64 lanes
    // cover the 64 columns of one token. Row reads are wave-uniform
    // ds_read_b128 broadcasts; stores 256B/instr contiguous. Sequential r4
    // order (bit-identical to R11).
    #pragma unroll
    for (int s = 0; s < 2; ++s) {
        const int slot = 2 * wid + s;
        const int tok  = blockIdx.x * 8 + slot;
        const float* slab = &w4s[slot * GSTRIDE];
        float* outp = out + (size_t)tok * 1024 + l;

        #pragma unroll
        for (int k = 0; k < 16; ++k) {
            const float4* wp = (const float4*)(slab + k * RSTRIDE);
            const float4 wa = wp[0], wb = wp[1], wc = wp[2], wd = wp[3];

            float acc = 0.f;
            acc = fmaf(wa.x, c4v[ 0], acc);
            acc = fmaf(wa.y, c4v[ 1], acc);
            acc = fmaf(wa.z, c4v[ 2], acc);
            acc = fmaf(wa.w, c4v[ 3], acc);
            acc = fmaf(wb.x, c4v[ 4], acc);
            acc = fmaf(wb.y, c4v[ 5], acc);
            acc = fmaf(wb.z, c4v[ 6], acc);
            acc = fmaf(wb.w, c4v[ 7], acc);
            acc = fmaf(wc.x, c4v[ 8], acc);
            acc = fmaf(wc.y, c4v[ 9], acc);
            acc = fmaf(wc.z, c4v[10], acc);
            acc = fmaf(wc.w, c4v[11], acc);
            acc = fmaf(wd.x, c4v[12], acc);
            acc = fmaf(wd.y, c4v[13], acc);
            acc = fmaf(wd.z, c4v[14], acc);
            acc = fmaf(wd.w, c4v[15], acc);

            if (tok < n_tokens)
                __builtin_nontemporal_store(acc, outp + (k << 6));
        }
    }
}

extern "C" void kernel_launch(void* const* d_in, const int* in_sizes, int n_in,
                              void* d_out, int out_size, void* d_ws, size_t ws_size,
                              hipStream_t stream) {
    const float* c0  = (const float*)d_in[0];
    const float* c1  = (const float*)d_in[1];
    const float* c2  = (const float*)d_in[2];
    const float* c3  = (const float*)d_in[3];
    const float* c4  = (const float*)d_in[4];
    const int*   idx = (const int*)d_in[5];
    float* out = (float*)d_out;

    const int n_tokens = in_sizes[5];              // 8 * 2048 = 16384
    const int grid = (n_tokens + 7) / 8;           // 2048
    tt_embed_kernel<<<grid, 256, 0, stream>>>(c0, c1, c2, c3, c4, idx, out, n_tokens);
}